// Round 1
// baseline (1028.320 us; speedup 1.0000x reference)
//
#include <hip/hip_runtime.h>

#define DEG 16
#define MAX_ITERS 32

// ---------------------------------------------------------------------------
// Kernel A: masked softmax over the D=16 neighbor slots of each node.
//   masked = fp - 1e7 * (adj == N); weights = softmax(masked, axis=-1)
// One thread per node, fully vectorized float4/int4 loads & stores.
// Writes weights into d_out (reused as scratch; final kernel overwrites it).
// ---------------------------------------------------------------------------
__global__ void softmax_k(const float* __restrict__ fp, const int* __restrict__ adj,
                          const int* __restrict__ nn, float* __restrict__ wout,
                          int nodes) {
    int i = blockIdx.x * blockDim.x + threadIdx.x;
    if (i >= nodes) return;
    const int N = *nn;
    const size_t base = (size_t)i * DEG;
    const float4* f4 = (const float4*)(fp + base);
    const int4*   a4 = (const int4*)(adj + base);
    float v[DEG];
#pragma unroll
    for (int k = 0; k < DEG / 4; ++k) {
        float4 f = f4[k];
        int4   a = a4[k];
        v[4*k+0] = (a.x == N) ? f.x - 1e7f : f.x;
        v[4*k+1] = (a.y == N) ? f.y - 1e7f : f.y;
        v[4*k+2] = (a.z == N) ? f.z - 1e7f : f.z;
        v[4*k+3] = (a.w == N) ? f.w - 1e7f : f.w;
    }
    float m = v[0];
#pragma unroll
    for (int j = 1; j < DEG; ++j) m = fmaxf(m, v[j]);
    float s = 0.f;
#pragma unroll
    for (int j = 0; j < DEG; ++j) { v[j] = expf(v[j] - m); s += v[j]; }
    float inv = 1.f / s;
    float4* w4 = (float4*)(wout + base);
#pragma unroll
    for (int k = 0; k < DEG / 4; ++k) {
        float4 o;
        o.x = v[4*k+0] * inv;
        o.y = v[4*k+1] * inv;
        o.z = v[4*k+2] * inv;
        o.w = v[4*k+3] * inv;
        w4[k] = o;
    }
}

// ---------------------------------------------------------------------------
// Kernel B: per-edge precompute (iteration-invariant).
//   flat_src[e] = bidx*N + src   (index into the per-node R array)
//   e_w[e]      = weights[flat_src, slot]
// Padded edges resolve to weights[b,0,VALID] == 0.0f exactly (softmax of a
// -1e7-masked slot underflows), so they contribute nothing downstream.
// ---------------------------------------------------------------------------
__global__ void gather_k(const int* __restrict__ in_idx, const float* __restrict__ w,
                         const int* __restrict__ nn, int* __restrict__ e_src,
                         float* __restrict__ e_w, int edges) {
    int e = blockIdx.x * blockDim.x + threadIdx.x;
    if (e >= edges) return;
    const int N = *nn;
    size_t e3 = 3 * (size_t)e;
    int b  = in_idx[e3 + 0];
    int s  = in_idx[e3 + 1];
    int sl = in_idx[e3 + 2];
    int fi = b * N + s;
    e_src[e] = fi;
    e_w[e]   = w[(size_t)fi * DEG + sl];
}

// ---------------------------------------------------------------------------
// Kernel C (x32): per-node scalar fixed-point step.
//   R_out[i] = relu( Σ_d e_w[i,d] * R_in[e_src[i,d]] - demand[i] )
// 128 B coalesced edge-table load per thread + 16 scattered 4 B R gathers
// (R is 1.6 MB -> L2-resident).
// ---------------------------------------------------------------------------
__global__ void iter_k(const int* __restrict__ e_src, const float* __restrict__ e_w,
                       const float* __restrict__ dem, const float* __restrict__ Rin,
                       float* __restrict__ Rout, int nodes) {
    int i = blockIdx.x * blockDim.x + threadIdx.x;
    if (i >= nodes) return;
    const size_t base = (size_t)i * DEG;
    const int4*   s4 = (const int4*)(e_src + base);
    const float4* w4 = (const float4*)(e_w + base);
    float acc = 0.f;
#pragma unroll
    for (int k = 0; k < DEG / 4; ++k) {
        int4   s = s4[k];
        float4 w = w4[k];
        acc += w.x * Rin[s.x];
        acc += w.y * Rin[s.y];
        acc += w.z * Rin[s.z];
        acc += w.w * Rin[s.w];
    }
    float r = acc - dem[i];
    Rout[i] = r > 0.f ? r : 0.f;
}

// ---------------------------------------------------------------------------
// Kernel D: flow_out[i,d] = weights[i,d] * R_32[i]  (in-place on d_out)
// ---------------------------------------------------------------------------
__global__ void final_k(const float* __restrict__ w, const float* __restrict__ R,
                        float* __restrict__ out, int nodes) {
    int i = blockIdx.x * blockDim.x + threadIdx.x;
    if (i >= nodes) return;
    float r = R[i];
    const size_t base = (size_t)i * DEG;
    const float4* w4 = (const float4*)(w + base);
    float4* o4 = (float4*)(out + base);
#pragma unroll
    for (int k = 0; k < DEG / 4; ++k) {
        float4 v = w4[k];
        v.x *= r; v.y *= r; v.z *= r; v.w *= r;
        o4[k] = v;
    }
}

extern "C" void kernel_launch(void* const* d_in, const int* in_sizes, int n_in,
                              void* d_out, int out_size, void* d_ws, size_t ws_size,
                              hipStream_t stream) {
    const float* fp  = (const float*)d_in[0];  // flow_proportions [B,N,D]
    const float* dem = (const float*)d_in[1];  // demands          [B,N,1]
    const int*   adj = (const int*)d_in[2];    // adj_lst          [B,N,D]
    const int*   idx = (const int*)d_in[3];    // in_indices       [B,N,D,3]
    const int*   nn  = (const int*)d_in[4];    // num_nodes        scalar

    const int edges = in_sizes[0];             // B*N*D
    const int nodes = in_sizes[1];             // B*N

    float* weights = (float*)d_out;            // reuse d_out as weights scratch

    char* ws = (char*)d_ws;
    int*   e_src = (int*)ws;   ws += (size_t)edges * sizeof(int);
    float* e_w   = (float*)ws; ws += (size_t)edges * sizeof(float);
    float* R0    = (float*)ws; ws += (size_t)nodes * sizeof(float);
    float* R1    = (float*)ws;

    hipMemsetAsync(R0, 0, (size_t)nodes * sizeof(float), stream);

    const int blk = 256;
    const int gn = (nodes + blk - 1) / blk;
    const int ge = (edges + blk - 1) / blk;

    softmax_k<<<gn, blk, 0, stream>>>(fp, adj, nn, weights, nodes);
    gather_k<<<ge, blk, 0, stream>>>(idx, weights, nn, e_src, e_w, edges);

    float* a = R0;
    float* b = R1;
    for (int t = 0; t < MAX_ITERS; ++t) {
        iter_k<<<gn, blk, 0, stream>>>(e_src, e_w, dem, a, b, nodes);
        float* tmp = a; a = b; b = tmp;
    }

    final_k<<<gn, blk, 0, stream>>>(weights, a, (float*)d_out, nodes);
}

// Round 2
// 1027.086 us; speedup vs baseline: 1.0012x; 1.0012x over previous
//
#include <hip/hip_runtime.h>
#include <hip/hip_cooperative_groups.h>

namespace cg = cooperative_groups;

#define DEG 16
#define MAX_ITERS 32

// ===========================================================================
// COOPERATIVE FUSED PATH
// One persistent thread per node. Phases:
//   0: masked softmax of own row  -> weights (d_out)
//   sync
//   1: gather 16 (src, w) pairs into REGISTERS (iteration-invariant)
//   2: R_1 = relu(-demand)  (R_0 = 0 so no gathers needed); store; sync
//   3: 31 x { r = relu(sum w[k]*R[src[k]] - dem); store; sync }
//   4: flow[i,:] = own_weights_row * r   (r already in register)
// Per-iteration traffic: 6.4M scattered 4B gathers from a 1.6 MB L2-resident
// R array + 1.6 MB store. The 51.2 MB edge table lives in registers.
// ===========================================================================
__global__ __launch_bounds__(256, 7)
void fused_k(const float* __restrict__ fp, const int* __restrict__ adj,
             const int* __restrict__ in_idx, const float* __restrict__ dem,
             const int* __restrict__ nn, float* __restrict__ wout,
             float* __restrict__ Ra, float* __restrict__ Rb, int nodes) {
    cg::grid_group grid = cg::this_grid();
    const int i = blockIdx.x * blockDim.x + threadIdx.x;
    const bool act = (i < nodes);
    const int N = *nn;
    const size_t base = (size_t)i * DEG;

    // ---- phase 0: masked softmax of own row ----
    if (act) {
        const float4* f4 = (const float4*)(fp + base);
        const int4*   a4 = (const int4*)(adj + base);
        float v[DEG];
#pragma unroll
        for (int k = 0; k < DEG / 4; ++k) {
            float4 f = f4[k];
            int4   a = a4[k];
            v[4*k+0] = (a.x == N) ? f.x - 1e7f : f.x;
            v[4*k+1] = (a.y == N) ? f.y - 1e7f : f.y;
            v[4*k+2] = (a.z == N) ? f.z - 1e7f : f.z;
            v[4*k+3] = (a.w == N) ? f.w - 1e7f : f.w;
        }
        float m = v[0];
#pragma unroll
        for (int j = 1; j < DEG; ++j) m = fmaxf(m, v[j]);
        float s = 0.f;
#pragma unroll
        for (int j = 0; j < DEG; ++j) { v[j] = __expf(v[j] - m); s += v[j]; }
        float inv = 1.f / s;
        float4* w4 = (float4*)(wout + base);
#pragma unroll
        for (int k = 0; k < DEG / 4; ++k) {
            float4 o;
            o.x = v[4*k+0] * inv;
            o.y = v[4*k+1] * inv;
            o.z = v[4*k+2] * inv;
            o.w = v[4*k+3] * inv;
            w4[k] = o;
        }
    }
    __threadfence();
    grid.sync();   // weights visible to all blocks

    // ---- phase 1: gather iteration-invariant edge table into registers ----
    int   src[DEG];
    float w[DEG];
    float dval = 0.f;
    if (act) {
        dval = dem[i];
        const int* t = in_idx + 3 * base;
#pragma unroll
        for (int k = 0; k < DEG; ++k) {
            int b  = t[3*k + 0];
            int s  = t[3*k + 1];
            int sl = t[3*k + 2];
            int fi = b * N + s;
            src[k] = fi;
            w[k]   = wout[(size_t)fi * DEG + sl];   // padded slot -> exactly 0.0f
        }
    } else {
#pragma unroll
        for (int k = 0; k < DEG; ++k) { src[k] = 0; w[k] = 0.f; }
    }

    // ---- phase 2: iteration 1 analytically (R_0 == 0) ----
    float r = fmaxf(-dval, 0.f);
    if (act) Ra[i] = r;
    __threadfence();
    grid.sync();

    // ---- phase 3: iterations 2..32 ----
    float* Rin  = Ra;
    float* Rout = Rb;
    for (int t = 1; t < MAX_ITERS; ++t) {
        if (act) {
            float acc = 0.f;
#pragma unroll
            for (int k = 0; k < DEG; ++k) acc += w[k] * Rin[src[k]];
            r = fmaxf(acc - dval, 0.f);
            Rout[i] = r;
        }
        __threadfence();
        grid.sync();
        float* tmp = Rin; Rin = Rout; Rout = tmp;
    }

    // ---- phase 4: epilogue, flow = own_weights * r ----
    if (act) {
        float4* w4 = (float4*)(wout + base);
#pragma unroll
        for (int k = 0; k < DEG / 4; ++k) {
            float4 v = w4[k];
            v.x *= r; v.y *= r; v.z *= r; v.w *= r;
            w4[k] = v;
        }
    }
}

// ===========================================================================
// FALLBACK PATH (round-1 kernels) — used only if cooperative co-residency
// is not available for this grid on this device.
// ===========================================================================
__global__ void softmax_k(const float* __restrict__ fp, const int* __restrict__ adj,
                          const int* __restrict__ nn, float* __restrict__ wout,
                          int nodes) {
    int i = blockIdx.x * blockDim.x + threadIdx.x;
    if (i >= nodes) return;
    const int N = *nn;
    const size_t base = (size_t)i * DEG;
    const float4* f4 = (const float4*)(fp + base);
    const int4*   a4 = (const int4*)(adj + base);
    float v[DEG];
#pragma unroll
    for (int k = 0; k < DEG / 4; ++k) {
        float4 f = f4[k];
        int4   a = a4[k];
        v[4*k+0] = (a.x == N) ? f.x - 1e7f : f.x;
        v[4*k+1] = (a.y == N) ? f.y - 1e7f : f.y;
        v[4*k+2] = (a.z == N) ? f.z - 1e7f : f.z;
        v[4*k+3] = (a.w == N) ? f.w - 1e7f : f.w;
    }
    float m = v[0];
#pragma unroll
    for (int j = 1; j < DEG; ++j) m = fmaxf(m, v[j]);
    float s = 0.f;
#pragma unroll
    for (int j = 0; j < DEG; ++j) { v[j] = __expf(v[j] - m); s += v[j]; }
    float inv = 1.f / s;
    float4* w4 = (float4*)(wout + base);
#pragma unroll
    for (int k = 0; k < DEG / 4; ++k) {
        float4 o;
        o.x = v[4*k+0] * inv;
        o.y = v[4*k+1] * inv;
        o.z = v[4*k+2] * inv;
        o.w = v[4*k+3] * inv;
        w4[k] = o;
    }
}

__global__ void gather_k(const int* __restrict__ in_idx, const float* __restrict__ w,
                         const int* __restrict__ nn, int* __restrict__ e_src,
                         float* __restrict__ e_w, int edges) {
    int e = blockIdx.x * blockDim.x + threadIdx.x;
    if (e >= edges) return;
    const int N = *nn;
    size_t e3 = 3 * (size_t)e;
    int b  = in_idx[e3 + 0];
    int s  = in_idx[e3 + 1];
    int sl = in_idx[e3 + 2];
    int fi = b * N + s;
    e_src[e] = fi;
    e_w[e]   = w[(size_t)fi * DEG + sl];
}

__global__ void iter_k(const int* __restrict__ e_src, const float* __restrict__ e_w,
                       const float* __restrict__ dem, const float* __restrict__ Rin,
                       float* __restrict__ Rout, int nodes) {
    int i = blockIdx.x * blockDim.x + threadIdx.x;
    if (i >= nodes) return;
    const size_t base = (size_t)i * DEG;
    const int4*   s4 = (const int4*)(e_src + base);
    const float4* w4 = (const float4*)(e_w + base);
    float acc = 0.f;
#pragma unroll
    for (int k = 0; k < DEG / 4; ++k) {
        int4   s = s4[k];
        float4 w = w4[k];
        acc += w.x * Rin[s.x];
        acc += w.y * Rin[s.y];
        acc += w.z * Rin[s.z];
        acc += w.w * Rin[s.w];
    }
    float r = acc - dem[i];
    Rout[i] = r > 0.f ? r : 0.f;
}

__global__ void final_k(const float* __restrict__ w, const float* __restrict__ R,
                        float* __restrict__ out, int nodes) {
    int i = blockIdx.x * blockDim.x + threadIdx.x;
    if (i >= nodes) return;
    float r = R[i];
    const size_t base = (size_t)i * DEG;
    const float4* w4 = (const float4*)(w + base);
    float4* o4 = (float4*)(out + base);
#pragma unroll
    for (int k = 0; k < DEG / 4; ++k) {
        float4 v = w4[k];
        v.x *= r; v.y *= r; v.z *= r; v.w *= r;
        o4[k] = v;
    }
}

extern "C" void kernel_launch(void* const* d_in, const int* in_sizes, int n_in,
                              void* d_out, int out_size, void* d_ws, size_t ws_size,
                              hipStream_t stream) {
    const float* fp  = (const float*)d_in[0];  // flow_proportions [B,N,D]
    const float* dem = (const float*)d_in[1];  // demands          [B,N,1]
    const int*   adj = (const int*)d_in[2];    // adj_lst          [B,N,D]
    const int*   idx = (const int*)d_in[3];    // in_indices       [B,N,D,3]
    const int*   nn  = (const int*)d_in[4];    // num_nodes        scalar

    const int edges = in_sizes[0];             // B*N*D
    const int nodes = in_sizes[1];             // B*N

    float* weights = (float*)d_out;

    char* ws = (char*)d_ws;
    int*   e_src = (int*)ws;   ws += (size_t)edges * sizeof(int);
    float* e_w   = (float*)ws; ws += (size_t)edges * sizeof(float);
    float* R0    = (float*)ws; ws += (size_t)nodes * sizeof(float);
    float* R1    = (float*)ws;

    const int blk = 256;
    const int gn = (nodes + blk - 1) / blk;
    const int ge = (edges + blk - 1) / blk;

    // Can the cooperative grid be co-resident?
    int dev = 0, cus = 0, maxBlk = 0;
    hipGetDevice(&dev);
    hipDeviceGetAttribute(&cus, hipDeviceAttributeMultiprocessorCount, dev);
    hipOccupancyMaxActiveBlocksPerMultiprocessor(&maxBlk, (const void*)fused_k, blk, 0);

    if ((long long)maxBlk * cus >= gn) {
        void* args[] = { (void*)&fp, (void*)&adj, (void*)&idx, (void*)&dem,
                         (void*)&nn, (void*)&weights, (void*)&R0, (void*)&R1,
                         (void*)&nodes };
        hipLaunchCooperativeKernel((const void*)fused_k, dim3(gn), dim3(blk),
                                   args, 0, stream);
    } else {
        // fallback: multi-launch path (round-1, known-correct)
        hipMemsetAsync(R0, 0, (size_t)nodes * sizeof(float), stream);
        softmax_k<<<gn, blk, 0, stream>>>(fp, adj, nn, weights, nodes);
        gather_k<<<ge, blk, 0, stream>>>(idx, weights, nn, e_src, e_w, edges);
        float* a = R0;
        float* b = R1;
        for (int t = 0; t < MAX_ITERS; ++t) {
            iter_k<<<gn, blk, 0, stream>>>(e_src, e_w, dem, a, b, nodes);
            float* tmp = a; a = b; b = tmp;
        }
        final_k<<<gn, blk, 0, stream>>>(weights, a, (float*)d_out, nodes);
    }
}